// Round 1
// baseline (169.421 us; speedup 1.0000x reference)
//
#include <hip/hip_runtime.h>

// Compact bilinear pooling, algebraically restructured:
//   out[b, (h1[c1]+h2[c2]) % D] += s1[c1]*s2[c2] * sum_hw x1[b,hw,c1]*x2[b,hw,c2]
// i.e. batched Gram GEMM (K=196) + sparse circular-conv scatter. No FFT.

#define NB   32
#define HW   196
#define CC   512
#define DD   8192
#define TM   128
#define TN   128
#define KT   14
#define NTHR 256

__global__ __launch_bounds__(NTHR) void cbp_fused_kernel(
    const float* __restrict__ x1, const float* __restrict__ x2,
    const float* __restrict__ s1, const float* __restrict__ s2,
    const int*   __restrict__ h1, const int*   __restrict__ h2,
    float* __restrict__ out)
{
    __shared__ float As[KT][TM];    // 7 KB
    __shared__ float Bs[KT][TN];    // 7 KB
    __shared__ float accD[DD];      // 32 KB  (per-block circular-conv accumulator)

    const int bid = blockIdx.x;
    const int b   = bid >> 4;
    const int t1  = (bid >> 2) & 3;   // c1 tile index (4 tiles of 128)
    const int t2  = bid & 3;          // c2 tile index
    const int tid = threadIdx.x;

    // zero the D-bucket accumulator (synced by first barrier in K-loop)
    for (int i = tid; i < DD; i += NTHR) accD[i] = 0.0f;

    const float* X1 = x1 + (size_t)b * HW * CC + t1 * TM;
    const float* X2 = x2 + (size_t)b * HW * CC + t2 * TN;

    float acc[8][8];
    #pragma unroll
    for (int i = 0; i < 8; ++i)
        #pragma unroll
        for (int j = 0; j < 8; ++j) acc[i][j] = 0.0f;

    const int tr = tid >> 4;   // 0..15
    const int tc = tid & 15;   // 0..15

    for (int k0 = 0; k0 < HW; k0 += KT) {
        __syncthreads();
        // stage KT x 128 panels of X1,X2 (float4, coalesced; c-stride 1)
        for (int i = tid; i < KT * (TM / 4); i += NTHR) {
            int row = i / (TM / 4);
            int col = (i % (TM / 4)) * 4;
            *(float4*)&As[row][col] = *(const float4*)&X1[(size_t)(k0 + row) * CC + col];
            *(float4*)&Bs[row][col] = *(const float4*)&X2[(size_t)(k0 + row) * CC + col];
        }
        __syncthreads();
        #pragma unroll
        for (int kk = 0; kk < KT; ++kk) {
            float a[8], bb[8];
            #pragma unroll
            for (int i = 0; i < 8; ++i) a[i]  = As[kk][tr * 8 + i];
            #pragma unroll
            for (int j = 0; j < 8; ++j) bb[j] = Bs[kk][tc * 8 + j];
            #pragma unroll
            for (int i = 0; i < 8; ++i)
                #pragma unroll
                for (int j = 0; j < 8; ++j)
                    acc[i][j] = fmaf(a[i], bb[j], acc[i][j]);
        }
    }

    // per-thread hash/sign metadata (8 c1 rows, 8 c2 cols)
    const int c1base = t1 * TM + tr * 8;
    const int c2base = t2 * TN + tc * 8;
    int hh1[8], hh2[8];
    float ss1[8], ss2[8];
    #pragma unroll
    for (int i = 0; i < 8; ++i) { hh1[i] = h1[c1base + i]; ss1[i] = s1[c1base + i]; }
    #pragma unroll
    for (int j = 0; j < 8; ++j) { hh2[j] = h2[c2base + j]; ss2[j] = s2[c2base + j]; }

    // scatter 64 products into the D-bucket LDS accumulator
    #pragma unroll
    for (int i = 0; i < 8; ++i) {
        #pragma unroll
        for (int j = 0; j < 8; ++j) {
            int pos = (hh1[i] + hh2[j]) & (DD - 1);
            atomicAdd(&accD[pos], ss1[i] * ss2[j] * acc[i][j]);
        }
    }
    __syncthreads();

    // merge block-local buckets into the global output (device-scope atomics)
    float* ob = out + (size_t)b * DD;
    for (int i = tid; i < DD; i += NTHR)
        atomicAdd(&ob[i], accD[i]);
}

extern "C" void kernel_launch(void* const* d_in, const int* in_sizes, int n_in,
                              void* d_out, int out_size, void* d_ws, size_t ws_size,
                              hipStream_t stream) {
    const float* x1 = (const float*)d_in[0];
    const float* x2 = (const float*)d_in[1];
    const float* s1 = (const float*)d_in[2];
    const float* s2 = (const float*)d_in[3];
    const int*   h1 = (const int*)d_in[4];
    const int*   h2 = (const int*)d_in[5];
    float* out = (float*)d_out;

    // d_out is poisoned (0xAA) before every launch; we accumulate with atomics,
    // so zero it first (stream-ordered, graph-capture safe).
    hipMemsetAsync(out, 0, (size_t)out_size * sizeof(float), stream);

    dim3 grid(NB * 4 * 4);   // 32 batches x 4x4 tiles of the 512x512 Gram matrix
    dim3 block(NTHR);
    cbp_fused_kernel<<<grid, block, 0, stream>>>(x1, x2, s1, s2, h1, h2, out);
}